// Round 2
// baseline (1259.382 us; speedup 1.0000x reference)
//
#include <hip/hip_runtime.h>
#include <hip/hip_bf16.h>

typedef __attribute__((ext_vector_type(8))) short bf16x8;
typedef __attribute__((ext_vector_type(4))) float f32x4;

#define B_SZ 64
#define L_SZ 1024
#define D_SZ 64
#define SCALE 0.125f

__device__ __forceinline__ short f2bf(float f) {
    union { float f; unsigned u; } v; v.f = f;
    unsigned r = (v.u + 0x7fffu + ((v.u >> 16) & 1u)) >> 16;  // RNE
    return (short)r;
}

__device__ __forceinline__ bf16x8 cvt8(const float* __restrict__ p) {
    f32x4 a = *(const f32x4*)p;
    f32x4 b = *(const f32x4*)(p + 4);
    bf16x8 r;
    r[0] = f2bf(a[0]); r[1] = f2bf(a[1]); r[2] = f2bf(a[2]); r[3] = f2bf(a[3]);
    r[4] = f2bf(b[0]); r[5] = f2bf(b[1]); r[6] = f2bf(b[2]); r[7] = f2bf(b[3]);
    return r;
}

#define MFMA(A, Bf, C) __builtin_amdgcn_mfma_f32_16x16x32_bf16(A, Bf, C, 0, 0, 0)

// ---------------------------------------------------------------------------
// Pre-pass 1: f32 -> bf16, same layout. n8 = element count / 8.
// ---------------------------------------------------------------------------
__global__ void cvt_bf16_k(const float* __restrict__ src, short* __restrict__ dst, int n8) {
    const int stride = gridDim.x * blockDim.x;
    for (int i = blockIdx.x * blockDim.x + threadIdx.x; i < n8; i += stride) {
        *(bf16x8*)(dst + (size_t)i * 8) = cvt8(src + (size_t)i * 8);
    }
}

// ---------------------------------------------------------------------------
// Pre-pass 2: src [outer][1024][64] f32 -> dst [outer][64][1024] bf16.
// Block 256 threads, grid (16 k-tiles, outer). LDS-tiled 64x64 transpose.
// ---------------------------------------------------------------------------
#define TP 72   // tile pitch (shorts): 144 B rows -> write banks spread, 16B-aligned
__global__ void tr64_bf16_k(const float* __restrict__ src, short* __restrict__ dst) {
    __shared__ __attribute__((aligned(16))) short tile[64 * TP];
    const int kt = blockIdx.x;
    const size_t o = blockIdx.y;
    const int tid = threadIdx.x;
    {
        const int rr = tid >> 2, c0 = (tid & 3) << 4;
        const float* sp = src + (o * L_SZ + (size_t)(kt * 64 + rr)) * D_SZ + c0;
        *(bf16x8*)(tile + rr * TP + c0)     = cvt8(sp);
        *(bf16x8*)(tile + rr * TP + c0 + 8) = cvt8(sp + 8);
    }
    __syncthreads();
    {
        const int d = tid >> 2, k4 = (tid & 3) << 4;
        bf16x8 o0, o1;
#pragma unroll
        for (int j = 0; j < 8; ++j) {
            o0[j] = tile[(k4 + j) * TP + d];
            o1[j] = tile[(k4 + 8 + j) * TP + d];
        }
        short* dp = dst + (o * 64 + (size_t)d) * L_SZ + kt * 64 + k4;
        *(bf16x8*)dp       = o0;
        *(bf16x8*)(dp + 8) = o1;
    }
}

// ---------------------------------------------------------------------------
// Main kernel (bf16 fast path). 16 batches x 16 queries per block, 8 waves in
// 2 k-groups of 4. All MFMA operands are single 16-B vector loads; P exchanged
// through a swizzled bf16 LDS buffer; l summed in registers. LDS = 128 KiB.
// ---------------------------------------------------------------------------
__global__ __launch_bounds__(512, 2) void rpr_attn_bf16(
    const short* __restrict__ Qb, const short* __restrict__ Kb,
    const short* __restrict__ Vt, const short* __restrict__ PKb,
    const short* __restrict__ PVt, const int* __restrict__ VLEN,
    float* __restrict__ OUT)
{
    // SA: f32 score exchange, [g][row = b_local*16+q_local][k 0..31], 128-B rows,
    // XOR-swizzled by ((b^q)&7)<<4 on the byte offset. 64 KB.
    __shared__ __attribute__((aligned(16))) float SA[2][256 * 32];
    // PB: bf16 P, [g][row][64 shorts], 128-B rows, same XOR swizzle. 64 KB.
    __shared__ __attribute__((aligned(16))) short PB[2][256 * 64];

    const int tid = threadIdx.x;
    const int wave = tid >> 6, lane = tid & 63;
    const int g = wave >> 2, r = wave & 3;
    const int lane15 = lane & 15, quad = lane >> 4;

    // XCD-aware swizzle: the 4 batch-tiles of one q-tile land on the same XCD
    // (256 blocks, 8 XCDs -> per-XCD L2 shares the pos tables).
    const int n = blockIdx.x;
    const int l = (n & 7) * 32 + (n >> 3);
    const int b0 = (l & 3) * 16;
    const int q0 = (l >> 2) * 16;

    char* sa = (char*)&SA[g][0];
    char* pb = (char*)&PB[g][0];

    // ---- Q fragments (bf16, single 16-B loads) ----
    bf16x8 qa[4][2], qp[4][2];
    int vl[4];
#pragma unroll
    for (int j = 0; j < 4; ++j) {
        const int bl = r * 4 + j;
        vl[j] = VLEN[b0 + bl];
        const short* pc = Qb + ((b0 + bl) * L_SZ + q0 + lane15) * D_SZ + quad * 8;
        qa[j][0] = *(const bf16x8*)pc;
        qa[j][1] = *(const bf16x8*)(pc + 32);
        const short* pp = Qb + ((b0 + lane15) * L_SZ + q0 + bl) * D_SZ + quad * 8;
        qp[j][0] = *(const bf16x8*)pp;
        qp[j][1] = *(const bf16x8*)(pp + 32);
    }

    f32x4 Oc[4][4], Op[4][4];
    float es[4][4];
#pragma unroll
    for (int j = 0; j < 4; ++j)
#pragma unroll
        for (int nt = 0; nt < 4; ++nt) {
            Oc[j][nt] = (f32x4){0.f, 0.f, 0.f, 0.f};
            Op[j][nt] = (f32x4){0.f, 0.f, 0.f, 0.f};
            es[j][nt] = 0.f;
        }

    for (int it = 0; it < 16; ++it) {
        const int kb = g * 512 + it * 32;

        // ---- phase 1: pos scores S_p[q](b x k) -> SA[b][q][k] (f32, swizzled) ----
#pragma unroll
        for (int j = 0; j < 4; ++j) {
            const int ql = r * 4 + j;
#pragma unroll
            for (int c = 0; c < 2; ++c) {
                const short* bp = PKb + ((q0 + ql) * L_SZ + kb + c * 16 + lane15) * D_SZ + quad * 8;
                f32x4 acc = (f32x4){0.f, 0.f, 0.f, 0.f};
                acc = MFMA(qp[j][0], *(const bf16x8*)bp, acc);
                acc = MFMA(qp[j][1], *(const bf16x8*)(bp + 32), acc);
#pragma unroll
                for (int i = 0; i < 4; ++i) {
                    const int brow = quad * 4 + i;
                    const int off = (((brow * 16 + ql) * 32 + c * 16 + lane15) * 4)
                                    ^ (((brow ^ ql) & 7) << 4);
                    *(float*)(sa + off) = acc[i];
                }
            }
        }
        __syncthreads();

        // ---- phase 2: content scores, combine, mask, exp -> P (bf16, swizzled) ----
#pragma unroll
        for (int j = 0; j < 4; ++j) {
            const int bl = r * 4 + j;
#pragma unroll
            for (int c = 0; c < 2; ++c) {
                const short* bp = Kb + ((b0 + bl) * L_SZ + kb + c * 16 + lane15) * D_SZ + quad * 8;
                f32x4 acc = (f32x4){0.f, 0.f, 0.f, 0.f};
                acc = MFMA(qa[j][0], *(const bf16x8*)bp, acc);
                acc = MFMA(qa[j][1], *(const bf16x8*)(bp + 32), acc);
                const int kg = kb + c * 16 + lane15;
#pragma unroll
                for (int i = 0; i < 4; ++i) {
                    const int q = quad * 4 + i;
                    const int soff = (((bl * 16 + q) * 32 + c * 16 + lane15) * 4)
                                     ^ (((bl ^ q) & 7) << 4);
                    const float s = (acc[i] + *(const float*)(sa + soff)) * SCALE;
                    float e;
                    if (vl[j] == 0)       e = 1.0f;          // fully-masked row -> uniform attn
                    else if (kg < vl[j])  e = __expf(s);
                    else                  e = 0.0f;
                    es[j][i] += e;
                    const int poff = (((bl * 16 + q) * 64 + c * 16 + lane15) * 2)
                                     ^ (((bl ^ q) & 7) << 4);
                    *(short*)(pb + poff) = f2bf(e);
                }
            }
        }
        __syncthreads();

        // ---- phase 3: PV contractions, operands straight from LDS-P and Vt/PVt ----
        // content: Oc[b] += P[b](q x k) * V[b](k x d)
#pragma unroll
        for (int j = 0; j < 4; ++j) {
            const int bl = r * 4 + j;
            const int aoff = (((bl * 16 + lane15) * 64) * 2 + quad * 16)
                             ^ (((bl ^ lane15) & 7) << 4);
            const bf16x8 af = *(const bf16x8*)(pb + aoff);
            const short* vb = Vt + ((b0 + bl) * 64 + lane15) * L_SZ + kb + quad * 8;
#pragma unroll
            for (int nt = 0; nt < 4; ++nt) {
                const bf16x8 bf = *(const bf16x8*)(vb + nt * 16 * L_SZ);
                Oc[j][nt] = MFMA(af, bf, Oc[j][nt]);
            }
        }
        // pos: Op[q] += P[q](b x k) * pos_v[q](k x d)
#pragma unroll
        for (int j = 0; j < 4; ++j) {
            const int ql = r * 4 + j;
            const int aoff = (((lane15 * 16 + ql) * 64) * 2 + quad * 16)
                             ^ (((lane15 ^ ql) & 7) << 4);
            const bf16x8 af = *(const bf16x8*)(pb + aoff);
            const short* vb = PVt + ((q0 + ql) * 64 + lane15) * L_SZ + kb + quad * 8;
#pragma unroll
            for (int nt = 0; nt < 4; ++nt) {
                const bf16x8 bf = *(const bf16x8*)(vb + nt * 16 * L_SZ);
                Op[j][nt] = MFMA(af, bf, Op[j][nt]);
            }
        }
        __syncthreads();   // protect SA/PB before next iteration
    }

    // ---- l reduction: sum es over the 16 lane15 lanes (k dim); store to PB overlay ----
    float* lball = (float*)&PB[0][0];   // PB is dead now; 512 floats
#pragma unroll
    for (int j = 0; j < 4; ++j)
#pragma unroll
        for (int i = 0; i < 4; ++i) {
            float s = es[j][i];
            s += __shfl_xor(s, 1);
            s += __shfl_xor(s, 2);
            s += __shfl_xor(s, 4);
            s += __shfl_xor(s, 8);
            if (lane15 == 0)
                lball[g * 256 + (r * 4 + j) * 16 + quad * 4 + i] = s;
        }

    // ---- epilogue: merge Oc/Op across roles and k-groups via LDS, normalize ----
    float* Obuf = &SA[0][0];   // 16384 floats, exactly the merge buffer size

    if (g == 0) {
#pragma unroll
        for (int j = 0; j < 4; ++j)
#pragma unroll
            for (int nt = 0; nt < 4; ++nt)
#pragma unroll
                for (int i = 0; i < 4; ++i)
                    Obuf[((r * 4 + j) * 16 + quad * 4 + i) * 64 + nt * 16 + lane15] = Oc[j][nt][i];
    }
    __syncthreads();
    if (g == 1) {
#pragma unroll
        for (int j = 0; j < 4; ++j)
#pragma unroll
            for (int nt = 0; nt < 4; ++nt)
#pragma unroll
                for (int i = 0; i < 4; ++i)
                    Obuf[((r * 4 + j) * 16 + quad * 4 + i) * 64 + nt * 16 + lane15] += Oc[j][nt][i];
    }
    __syncthreads();
    if (g == 0) {
#pragma unroll
        for (int j = 0; j < 4; ++j)
#pragma unroll
            for (int nt = 0; nt < 4; ++nt)
#pragma unroll
                for (int i = 0; i < 4; ++i)
                    Obuf[((quad * 4 + i) * 16 + r * 4 + j) * 64 + nt * 16 + lane15] += Op[j][nt][i];
    }
    __syncthreads();
    if (g == 1) {
#pragma unroll
        for (int j = 0; j < 4; ++j)
#pragma unroll
            for (int nt = 0; nt < 4; ++nt)
#pragma unroll
                for (int i = 0; i < 4; ++i)
                    Obuf[((quad * 4 + i) * 16 + r * 4 + j) * 64 + nt * 16 + lane15] += Op[j][nt][i];
    }
    __syncthreads();

    for (int idx = tid; idx < 4096; idx += 512) {
        const int d4 = idx & 15, ql2 = (idx >> 4) & 15, bl2 = idx >> 8;
        const float li = lball[bl2 * 16 + ql2] + lball[256 + bl2 * 16 + ql2];
        const float rl = 1.0f / li;
        f32x4 o = *(const f32x4*)&Obuf[(bl2 * 16 + ql2) * 64 + d4 * 4];
        o[0] *= rl; o[1] *= rl; o[2] *= rl; o[3] *= rl;
        *(f32x4*)&OUT[((b0 + bl2) * L_SZ + q0 + ql2) * D_SZ + d4 * 4] = o;
    }
}

// ---------------------------------------------------------------------------
// Fallback kernel (previous verified best) — used only if ws_size too small.
// ---------------------------------------------------------------------------
#define KP 36          // k pitch (floats)
#define BPITCH 580     // 16*KP + 4
#define SA_SZ 9280     // 16*BPITCH floats per k-group

__global__ __launch_bounds__(512, 2) void rpr_attn(
    const float* __restrict__ Q, const float* __restrict__ Kt,
    const float* __restrict__ V, const float* __restrict__ PK,
    const float* __restrict__ PV, const int* __restrict__ VLEN,
    float* __restrict__ OUT)
{
    __shared__ float SA[2][SA_SZ];
    __shared__ float lbuf[2][256];

    const int tid = threadIdx.x;
    const int wave = tid >> 6, lane = tid & 63;
    const int g = wave >> 2, r = wave & 3;
    const int lane15 = lane & 15, quad = lane >> 4;
    const int b0 = blockIdx.x * 16;
    const int q0 = blockIdx.y * 16;

    float* sa = SA[g];

    bf16x8 qa[4][2], qp[4][2];
    int vl[4];
#pragma unroll
    for (int j = 0; j < 4; ++j) {
        const int bl = r * 4 + j;
        vl[j] = VLEN[b0 + bl];
        const float* pc = Q + ((b0 + bl) * L_SZ + q0 + lane15) * D_SZ + quad * 8;
        qa[j][0] = cvt8(pc); qa[j][1] = cvt8(pc + 32);
        const float* pp = Q + ((b0 + lane15) * L_SZ + q0 + bl) * D_SZ + quad * 8;
        qp[j][0] = cvt8(pp); qp[j][1] = cvt8(pp + 32);
    }

    f32x4 Oc[4][4], Op[4][4];
#pragma unroll
    for (int j = 0; j < 4; ++j)
#pragma unroll
        for (int nt = 0; nt < 4; ++nt) {
            Oc[j][nt] = (f32x4){0.f, 0.f, 0.f, 0.f};
            Op[j][nt] = (f32x4){0.f, 0.f, 0.f, 0.f};
        }
    float l_acc = 0.f;

    const int tg = r * 64 + lane;
    const int lb = tg >> 4, lq = tg & 15;

    for (int it = 0; it < 16; ++it) {
        const int kb = g * 512 + it * 32;

#pragma unroll
        for (int j = 0; j < 4; ++j) {
            const int ql = r * 4 + j;
#pragma unroll
            for (int c = 0; c < 2; ++c) {
                const float* bp = PK + ((q0 + ql) * L_SZ + kb + c * 16 + lane15) * D_SZ + quad * 8;
                f32x4 acc = (f32x4){0.f, 0.f, 0.f, 0.f};
                acc = MFMA(qp[j][0], cvt8(bp), acc);
                acc = MFMA(qp[j][1], cvt8(bp + 32), acc);
#pragma unroll
                for (int i = 0; i < 4; ++i)
                    sa[(quad * 4 + i) * BPITCH + ql * KP + c * 16 + lane15] = acc[i];
            }
        }
        __syncthreads();

#pragma unroll
        for (int j = 0; j < 4; ++j) {
            const int bl = r * 4 + j;
#pragma unroll
            for (int c = 0; c < 2; ++c) {
                const float* bp = Kt + ((b0 + bl) * L_SZ + kb + c * 16 + lane15) * D_SZ + quad * 8;
                f32x4 acc = (f32x4){0.f, 0.f, 0.f, 0.f};
                acc = MFMA(qa[j][0], cvt8(bp), acc);
                acc = MFMA(qa[j][1], cvt8(bp + 32), acc);
                const int kg = kb + c * 16 + lane15;
#pragma unroll
                for (int i = 0; i < 4; ++i) {
                    const int idx = bl * BPITCH + (quad * 4 + i) * KP + c * 16 + lane15;
                    const float s = (acc[i] + sa[idx]) * SCALE;
                    float e;
                    if (vl[j] == 0)       e = 1.0f;
                    else if (kg < vl[j])  e = __expf(s);
                    else                  e = 0.0f;
                    sa[idx] = e;
                }
            }
        }
        __syncthreads();

        {
            const float* row = sa + lb * BPITCH + lq * KP;
            float s = 0.f;
#pragma unroll
            for (int kk = 0; kk < 32; kk += 4) {
                f32x4 v4 = *(const f32x4*)(row + kk);
                s += v4[0] + v4[1] + v4[2] + v4[3];
            }
            l_acc += s;
        }
#pragma unroll
        for (int j = 0; j < 4; ++j) {
            const int bl = r * 4 + j;
            const bf16x8 af = cvt8(sa + bl * BPITCH + lane15 * KP + quad * 8);
            const float* vb = V + ((b0 + bl) * L_SZ + kb + quad * 8) * D_SZ + lane15;
#pragma unroll
            for (int nt = 0; nt < 4; ++nt) {
                bf16x8 bf;
#pragma unroll
                for (int jj = 0; jj < 8; ++jj) bf[jj] = f2bf(vb[jj * D_SZ + nt * 16]);
                Oc[j][nt] = MFMA(af, bf, Oc[j][nt]);
            }
        }
#pragma unroll
        for (int j = 0; j < 4; ++j) {
            const int ql = r * 4 + j;
            const bf16x8 af = cvt8(sa + lane15 * BPITCH + ql * KP + quad * 8);
            const float* vb = PV + ((q0 + ql) * L_SZ + kb + quad * 8) * D_SZ + lane15;
#pragma unroll
            for (int nt = 0; nt < 4; ++nt) {
                bf16x8 bf;
#pragma unroll
                for (int jj = 0; jj < 8; ++jj) bf[jj] = f2bf(vb[jj * D_SZ + nt * 16]);
                Op[j][nt] = MFMA(af, bf, Op[j][nt]);
            }
        }
        __syncthreads();
    }

    lbuf[g][tg] = l_acc;
    float* Obuf = &SA[0][0];

    if (g == 0) {
#pragma unroll
        for (int j = 0; j < 4; ++j)
#pragma unroll
            for (int nt = 0; nt < 4; ++nt)
#pragma unroll
                for (int i = 0; i < 4; ++i)
                    Obuf[((r * 4 + j) * 16 + quad * 4 + i) * 64 + nt * 16 + lane15] = Oc[j][nt][i];
    }
    __syncthreads();
    if (g == 1) {
#pragma unroll
        for (int j = 0; j < 4; ++j)
#pragma unroll
            for (int nt = 0; nt < 4; ++nt)
#pragma unroll
                for (int i = 0; i < 4; ++i)
                    Obuf[((r * 4 + j) * 16 + quad * 4 + i) * 64 + nt * 16 + lane15] += Oc[j][nt][i];
    }
    __syncthreads();
    if (g == 0) {
#pragma unroll
        for (int j = 0; j < 4; ++j)
#pragma unroll
            for (int nt = 0; nt < 4; ++nt)
#pragma unroll
                for (int i = 0; i < 4; ++i)
                    Obuf[((quad * 4 + i) * 16 + r * 4 + j) * 64 + nt * 16 + lane15] += Op[j][nt][i];
    }
    __syncthreads();
    if (g == 1) {
#pragma unroll
        for (int j = 0; j < 4; ++j)
#pragma unroll
            for (int nt = 0; nt < 4; ++nt)
#pragma unroll
                for (int i = 0; i < 4; ++i)
                    Obuf[((quad * 4 + i) * 16 + r * 4 + j) * 64 + nt * 16 + lane15] += Op[j][nt][i];
    }
    __syncthreads();

    for (int idx = tid; idx < 4096; idx += 512) {
        const int d4 = idx & 15, ql2 = (idx >> 4) & 15, bl2 = idx >> 8;
        const float li = lbuf[0][bl2 * 16 + ql2] + lbuf[1][bl2 * 16 + ql2];
        const float rl = 1.0f / li;
        f32x4 o = *(const f32x4*)&Obuf[(bl2 * 16 + ql2) * 64 + d4 * 4];
        o[0] *= rl; o[1] *= rl; o[2] *= rl; o[3] *= rl;
        *(f32x4*)&OUT[((b0 + bl2) * L_SZ + q0 + ql2) * D_SZ + d4 * 4] = o;
    }
}

extern "C" void kernel_launch(void* const* d_in, const int* in_sizes, int n_in,
                              void* d_out, int out_size, void* d_ws, size_t ws_size,
                              hipStream_t stream) {
    (void)in_sizes; (void)n_in; (void)out_size;
    const float* Q  = (const float*)d_in[0];
    const float* K  = (const float*)d_in[1];
    const float* V  = (const float*)d_in[2];
    const float* PK = (const float*)d_in[3];
    const float* PV = (const float*)d_in[4];
    const int*   VL = (const int*)d_in[5];
    float* OUT = (float*)d_out;

    // Workspace layout (bf16 = short):
    //   Qb  [64][1024][64]   4,194,304 elems
    //   Kb  [64][1024][64]   4,194,304
    //   Vt  [64][64][1024]   4,194,304   (V transposed)
    //   PKb [1024][1024][64] 67,108,864
    //   PVt [1024][64][1024] 67,108,864  (PV transposed)
    const size_t WS_NEEDED = (3ull * 4194304ull + 2ull * 67108864ull) * 2ull;  // 293,601,280 B

    if (d_ws != nullptr && ws_size >= WS_NEEDED) {
        short* Qb  = (short*)d_ws;
        short* Kb  = Qb + 4194304;
        short* Vt  = Kb + 4194304;
        short* PKb = Vt + 4194304;
        short* PVt = PKb + 67108864;

        cvt_bf16_k<<<dim3(1024), dim3(256), 0, stream>>>(Q, Qb, 524288);
        cvt_bf16_k<<<dim3(1024), dim3(256), 0, stream>>>(K, Kb, 524288);
        cvt_bf16_k<<<dim3(2048), dim3(256), 0, stream>>>(PK, PKb, 8388608);
        tr64_bf16_k<<<dim3(16, 64),   dim3(256), 0, stream>>>(V, Vt);
        tr64_bf16_k<<<dim3(16, 1024), dim3(256), 0, stream>>>(PV, PVt);

        rpr_attn_bf16<<<dim3(256), dim3(512), 0, stream>>>(Qb, Kb, Vt, PKb, PVt, VL, OUT);
    } else {
        dim3 grid(4, 64, 1);
        dim3 block(512, 1, 1);
        rpr_attn<<<grid, block, 0, stream>>>(Q, K, V, PK, PV, VL, OUT);
    }
}